// Round 8
// baseline (556.975 us; speedup 1.0000x reference)
//
#include <hip/hip_runtime.h>
#include <hip/hip_bf16.h>
#include <hip/hip_cooperative_groups.h>
#include <cstdint>

namespace cg = cooperative_groups;

#define EMBED   1024
#define NHEADS  16
#define HDIM    64
#define SEQ     2048
#define BSZ     2
#define MTOT    (BSZ*SEQ)   // 4096
#define NCLS    1000
#define NPAD    1024

typedef __attribute__((ext_vector_type(8))) short short8;
typedef __attribute__((ext_vector_type(4))) short short4v;
typedef __attribute__((ext_vector_type(4))) float float4v;

typedef __attribute__((address_space(3))) unsigned lds_uint;
typedef __attribute__((address_space(1))) const unsigned gbl_uint;

__device__ __forceinline__ void gl2lds16(const void* g, void* l) {
    __builtin_amdgcn_global_load_lds((gbl_uint*)g, (lds_uint*)l, 16, 0, 0);
}

#define WAITVM6() asm volatile("s_waitcnt vmcnt(6)" ::: "memory")
#define WAITVM0() asm volatile("s_waitcnt vmcnt(0)" ::: "memory")
#define BAR()     asm volatile("s_barrier" ::: "memory")

__device__ __forceinline__ void storeC(float* p, float v) { *p = v; }
__device__ __forceinline__ void storeC(__hip_bfloat16* p, float v) { *p = __float2bfloat16(v); }

#define XN4  ((MTOT*EMBED)/4)    // 1,048,576
#define WN4  ((EMBED*EMBED)/4)   // 262,144
#define GN4  (32*64*64/4)        // 32,768

struct KParams {
    const float* x; const float* Win; const float* b_in;
    const float* Wout; const float* b_out;
    float* out;
    __hip_bfloat16* xb; __hip_bfloat16* Winb; __hip_bfloat16* P; __hip_bfloat16* WeffT;
    float* G;
};

// ---------------------------------------------------------------------------
// GEMM phase: C[m][n] = sum_k A[m][k]*B[n][k] + bias[n]  (row-major, B^T)
// 128x64 tile, BK=64, XCD-aware decode of flat blk, XOR-swizzled LDS,
// double-buffered with raw s_barrier + vmcnt(6). Same body as R7 kernel.
// ---------------------------------------------------------------------------
template <typename CT>
__device__ __forceinline__ void gemm_phase(char* smem, int t, int blk,
        const __hip_bfloat16* __restrict__ A, const __hip_bfloat16* __restrict__ B,
        const float* __restrict__ bias, CT* __restrict__ C,
        int K, int nstore, int cstride, long bstride) {
    __hip_bfloat16* As = (__hip_bfloat16*)smem;            // 2 x 8192 elems (32 KiB)
    __hip_bfloat16* Bs = (__hip_bfloat16*)(smem + 32768);  // 2 x 4096 elems (16 KiB)

    const int xcd  = blk & 7;
    const int j    = blk >> 3;              // 0..63
    const int bm   = (xcd * 4 + (j & 3)) * 128;
    const int bn   = (j >> 2) * 64;
    const __hip_bfloat16* Bb = B + (long)(bm >> 11) * bstride;
    const int wave = t >> 6, lane = t & 63;
    const int wm   = (wave & 1) * 64, wn = (wave >> 1) * 32;
    const int lrow = lane & 15, lq = lane >> 4;

    const __hip_bfloat16* Arow[4];
    const __hip_bfloat16* Brow[2];
#pragma unroll
    for (int i = 0; i < 4; i++) {
        const int ci = i * 256 + t;
        const int r  = ci >> 3;
        const int sc = ((ci & 7) ^ (r & 7)) * 8;
        Arow[i] = A + (long)(bm + r) * K + sc;
    }
#pragma unroll
    for (int i = 0; i < 2; i++) {
        const int ci = i * 256 + t;
        const int r  = ci >> 3;
        const int sc = ((ci & 7) ^ (r & 7)) * 8;
        Brow[i] = Bb + (long)(bn + r) * K + sc;
    }

    float4v acc[4][2];
#pragma unroll
    for (int i = 0; i < 4; i++)
#pragma unroll
        for (int jj = 0; jj < 2; jj++) acc[i][jj] = (float4v){0.f, 0.f, 0.f, 0.f};

    const int nIter = K >> 6;   // 16

#define STAGE_TILE(k0, buf)                                                       \
    do {                                                                          \
        _Pragma("unroll")                                                         \
        for (int i = 0; i < 4; i++)                                               \
            gl2lds16(Arow[i] + (k0), (char*)(As + (buf) * 8192) + (i * 256 + t) * 16); \
        _Pragma("unroll")                                                         \
        for (int i = 0; i < 2; i++)                                               \
            gl2lds16(Brow[i] + (k0), (char*)(Bs + (buf) * 4096) + (i * 256 + t) * 16); \
    } while (0)

    STAGE_TILE(0, 0);

    for (int it = 0; it < nIter; ++it) {
        const int cur = it & 1, nxt = cur ^ 1;
        if (it + 1 < nIter) {
            STAGE_TILE((it + 1) << 6, nxt);
            WAITVM6();
        } else {
            WAITVM0();
        }
        BAR();

        const __hip_bfloat16* Ac = As + cur * 8192;
        const __hip_bfloat16* Bc = Bs + cur * 4096;
#pragma unroll
        for (int kk = 0; kk < 2; kk++) {
            short8 af[4], bf[2];
#pragma unroll
            for (int i = 0; i < 4; i++) {
                const int row = wm + i * 16 + lrow;
                const int sc  = (kk * 4 + lq) ^ (row & 7);
                af[i] = *(const short8*)(Ac + row * 64 + sc * 8);
            }
#pragma unroll
            for (int jj = 0; jj < 2; jj++) {
                const int row = wn + jj * 16 + lrow;
                const int sc  = (kk * 4 + lq) ^ (row & 7);
                bf[jj] = *(const short8*)(Bc + row * 64 + sc * 8);
            }
#pragma unroll
            for (int i = 0; i < 4; i++)
#pragma unroll
                for (int jj = 0; jj < 2; jj++)
                    acc[i][jj] = __builtin_amdgcn_mfma_f32_16x16x32_bf16(af[i], bf[jj], acc[i][jj], 0, 0, 0);
        }
        BAR();
    }
#undef STAGE_TILE

    float bv[2];
#pragma unroll
    for (int jj = 0; jj < 2; jj++) {
        const int gn = bn + wn + jj * 16 + lrow;
        bv[jj] = (gn < nstore) ? bias[gn] : 0.f;
    }
#pragma unroll
    for (int i = 0; i < 4; i++) {
        const int gm0 = bm + wm + i * 16 + lq * 4;
#pragma unroll
        for (int jj = 0; jj < 2; jj++) {
            const int gn = bn + wn + jj * 16 + lrow;
            if (gn < nstore) {
#pragma unroll
                for (int r = 0; r < 4; r++)
                    storeC(&C[(long)(gm0 + r) * cstride + gn], acc[i][jj][r] + bv[jj]);
            }
        }
    }
}

// ---------------------------------------------------------------------------
// Gram phase: G[bh] += P_chunk^T P_chunk (fp32 atomics). blk -> (bh, ck).
// ---------------------------------------------------------------------------
__device__ __forceinline__ void gram_phase(char* smem, int t, int blk,
        const __hip_bfloat16* __restrict__ P, float* __restrict__ G) {
    float (*Pl)[68] = (float(*)[68])smem;   // 128 x 68 = 34816 B
    const int bh = blk >> 4;     // 0..31
    const int ck = blk & 15;     // 0..15
    const int b = bh >> 4, h = bh & 15;
    const int row0 = b * SEQ + ck * 128;

#pragma unroll
    for (int it = 0; it < 4; it++) {
        const int ci = it * 256 + t;
        const int r = ci >> 3, c8 = (ci & 7) * 8;
        short8 v = *(const short8*)(P + (long)(row0 + r) * EMBED + h * HDIM + c8);
        float4v f0, f1;
#pragma unroll
        for (int u = 0; u < 4; u++) {
            f0[u] = __bfloat162float(((const __hip_bfloat16*)&v)[u]);
            f1[u] = __bfloat162float(((const __hip_bfloat16*)&v)[u + 4]);
        }
        *(float4v*)&Pl[r][c8]     = f0;
        *(float4v*)&Pl[r][c8 + 4] = f1;
    }
    __syncthreads();

    const int ty = t >> 4, tx = t & 15;
    float acc[4][4] = {};
    for (int k = 0; k < 128; k++) {
        float4v a  = *(const float4v*)&Pl[k][4 * ty];
        float4v bb = *(const float4v*)&Pl[k][4 * tx];
#pragma unroll
        for (int i = 0; i < 4; i++)
#pragma unroll
            for (int jj = 0; jj < 4; jj++) acc[i][jj] += a[i] * bb[jj];
    }
    float* Gh = G + bh * 4096;
#pragma unroll
    for (int i = 0; i < 4; i++)
#pragma unroll
        for (int jj = 0; jj < 4; jj++)
            atomicAdd(&Gh[(4 * ty + i) * 64 + 4 * tx + jj], acc[i][jj]);
}

// ---------------------------------------------------------------------------
// Weff phase: WeffT[b][n][64h+d1] = scale * sum_d Wout[n][64h+d]*G[b,h][d][d1]
// blk -> (n0t, h, b):  n0t = blk&15, h = (blk>>4)&15, b = blk>>8.
// ---------------------------------------------------------------------------
__device__ __forceinline__ void weff_phase(char* smem, int t, int blk,
        const float* __restrict__ Wout, const float* __restrict__ G,
        __hip_bfloat16* __restrict__ WeffT) {
    float (*Wl)[65] = (float(*)[65])smem;                 // 64 x 65 = 16640 B
    float (*Gl)[64] = (float(*)[64])(smem + 16640);       // 64 x 64 = 16384 B
    const int n0 = (blk & 15) * 64;
    const int h  = (blk >> 4) & 15;
    const int b  = blk >> 8;
    const float* Gh = G + (b * 16 + h) * 4096;

#pragma unroll
    for (int it = 0; it < 4; it++) {
        const int ci = it * 256 + t;
        const int r = ci >> 4, c4 = (ci & 15) * 4;
        const int gr = n0 + r;
        float4v v = (float4v){0.f, 0.f, 0.f, 0.f};
        if (gr < NCLS)
            v = *(const float4v*)(Wout + (long)gr * EMBED + h * HDIM + c4);
        Wl[r][c4 + 0] = v[0]; Wl[r][c4 + 1] = v[1];
        Wl[r][c4 + 2] = v[2]; Wl[r][c4 + 3] = v[3];
    }
#pragma unroll
    for (int it = 0; it < 4; it++) {
        const int ci = it * 256 + t;
        const int r = ci >> 4, c4 = (ci & 15) * 4;
        *(float4v*)&Gl[r][c4] = *(const float4v*)&Gh[r * 64 + c4];
    }
    __syncthreads();

    const int ty = t >> 4, tx = t & 15;
    float acc[4][4] = {};
    for (int k = 0; k < 64; k++) {
        const float a0 = Wl[4 * ty + 0][k];
        const float a1 = Wl[4 * ty + 1][k];
        const float a2 = Wl[4 * ty + 2][k];
        const float a3 = Wl[4 * ty + 3][k];
        float4v g = *(const float4v*)&Gl[k][4 * tx];
#pragma unroll
        for (int jj = 0; jj < 4; jj++) {
            acc[0][jj] += a0 * g[jj];
            acc[1][jj] += a1 * g[jj];
            acc[2][jj] += a2 * g[jj];
            acc[3][jj] += a3 * g[jj];
        }
    }
    const float scale = 1.0f / 32.0f;  // 1/sqrt(EMBED)
    __hip_bfloat16* Wt = WeffT + (long)b * EMBED * NPAD;
#pragma unroll
    for (int i = 0; i < 4; i++) {
        const int gr = n0 + 4 * ty + i;
        short4v ov;
#pragma unroll
        for (int jj = 0; jj < 4; jj++)
            ((__hip_bfloat16*)&ov)[jj] = __float2bfloat16(acc[i][jj] * scale);
        *(short4v*)(Wt + (long)gr * EMBED + h * HDIM + 4 * tx) = ov;
    }
}

// ---------------------------------------------------------------------------
// ONE cooperative kernel: conv -> GEMM1 -> gram -> weff -> GEMM2 with
// grid.sync() between phases. 512 blocks x 256 thr, 48 KiB LDS, 2 blocks/CU.
// Eliminates 4 inter-kernel launch gaps / pipeline drains.
// ---------------------------------------------------------------------------
__global__ __launch_bounds__(256, 2)
void fused_pipeline(KParams p) {
    __shared__ __align__(16) char smem[49152];
    cg::grid_group grid = cg::this_grid();
    const int t   = threadIdx.x;
    const int blk = blockIdx.x;

    // ---- P1: fp32->bf16 converts + G zero (grid-strided) ----
    {
        const long stride = 512L * 256;
        for (long i4 = (long)blk * 256 + t; i4 < XN4 + WN4; i4 += stride) {
            if (i4 < GN4)
                *(float4v*)(p.G + i4 * 4) = (float4v){0.f, 0.f, 0.f, 0.f};
            float4v v;
            __hip_bfloat16* dst;
            if (i4 < XN4) {
                v = *(const float4v*)(p.x + i4 * 4);
                dst = p.xb + i4 * 4;
            } else {
                const long jj = i4 - XN4;
                v = *(const float4v*)(p.Win + jj * 4);
                dst = p.Winb + jj * 4;
            }
            short4v o;
#pragma unroll
            for (int u = 0; u < 4; u++)
                ((__hip_bfloat16*)&o)[u] = __float2bfloat16(v[u]);
            *(short4v*)dst = o;
        }
    }
    __threadfence();
    grid.sync();

    // ---- P2: P = x @ W_in^T + b_in  [4096 x 1024] bf16 ----
    gemm_phase<__hip_bfloat16>(smem, t, blk, p.xb, p.Winb, p.b_in, p.P,
                               EMBED, NPAD, NPAD, 0);
    __threadfence();
    grid.sync();

    // ---- P3: G[bh] = P_h^T P_h ----
    gram_phase(smem, t, blk, p.P, p.G);
    __threadfence();
    grid.sync();

    // ---- P4: WeffT[b] = scale * (G . Wout^T) ----
    weff_phase(smem, t, blk, p.Wout, p.G, p.WeffT);
    __threadfence();
    grid.sync();

    // ---- P5: out = P @ WeffT^T + b_out  [4096 x 1000] fp32 ----
    gemm_phase<float>(smem, t, blk, p.P, p.WeffT, p.b_out, p.out,
                      EMBED, NCLS, NCLS, (long)EMBED * NPAD);
}

// ---------------------------------------------------------------------------
extern "C" void kernel_launch(void* const* d_in, const int* in_sizes, int n_in,
                              void* d_out, int out_size, void* d_ws, size_t ws_size,
                              hipStream_t stream) {
    char* ws = (char*)d_ws;
    KParams hp;
    hp.x     = (const float*)d_in[0];
    hp.Win   = (const float*)d_in[1];
    hp.b_in  = (const float*)d_in[2];
    hp.Wout  = (const float*)d_in[3];
    hp.b_out = (const float*)d_in[4];
    hp.out   = (float*)d_out;
    hp.xb    = (__hip_bfloat16*)(ws);                 // 8 MiB
    hp.Winb  = (__hip_bfloat16*)(ws + (8u  << 20));   // 2 MiB
    hp.P     = (__hip_bfloat16*)(ws + (10u << 20));   // 8 MiB
    hp.G     = (float*)(ws + (18u << 20));            // 512 KiB
    hp.WeffT = (__hip_bfloat16*)(ws + (19u << 20));   // 4 MiB (2 batches)

    void* args[] = { &hp };
    hipLaunchCooperativeKernel((void*)fused_pipeline, dim3(512), dim3(256),
                               args, 0, stream);
}

// Round 9
// 123.110 us; speedup vs baseline: 4.5242x; 4.5242x over previous
//
#include <hip/hip_runtime.h>
#include <hip/hip_bf16.h>
#include <cstdint>

#define EMBED   1024
#define NHEADS  16
#define HDIM    64
#define SEQ     2048
#define BSZ     2
#define MTOT    (BSZ*SEQ)   // 4096
#define NCLS    1000
#define NPAD    1024

typedef __attribute__((ext_vector_type(8))) short short8;
typedef __attribute__((ext_vector_type(4))) short short4v;
typedef __attribute__((ext_vector_type(4))) float float4v;

typedef __attribute__((address_space(3))) unsigned lds_uint;
typedef __attribute__((address_space(1))) const unsigned gbl_uint;

__device__ __forceinline__ void gl2lds16(const void* g, void* l) {
    __builtin_amdgcn_global_load_lds((gbl_uint*)g, (lds_uint*)l, 16, 0, 0);
}

#define WAITVM6() asm volatile("s_waitcnt vmcnt(6)" ::: "memory")
#define WAITVM0() asm volatile("s_waitcnt vmcnt(0)" ::: "memory")
#define BAR()     asm volatile("s_barrier" ::: "memory")

__device__ __forceinline__ void storeC(float* p, float v) { *p = v; }
__device__ __forceinline__ void storeC(__hip_bfloat16* p, float v) { *p = __float2bfloat16(v); }

__device__ __forceinline__ unsigned packbf2(float a, float b) {
    __hip_bfloat16 ha = __float2bfloat16(a), hb = __float2bfloat16(b);
    unsigned short ua, ub;
    __builtin_memcpy(&ua, &ha, 2); __builtin_memcpy(&ub, &hb, 2);
    return (unsigned)ua | ((unsigned)ub << 16);
}
// unaligned-to-16B LDS fragment load (rows stride 132 bf16 = 264 B, 8B-aligned)
__device__ __forceinline__ short8 lds8u(const __hip_bfloat16* p) {
    union { uint2 u[2]; short8 s; } v;
    v.u[0] = *(const uint2*)p;
    v.u[1] = *(const uint2*)(p + 4);
    return v.s;
}

// ---------------------------------------------------------------------------
// Convert fp32 x, W_in to bf16 ws copies; zero G. (W_out handled in weff.)
// ---------------------------------------------------------------------------
#define XN4  ((MTOT*EMBED)/4)    // 1,048,576
#define WN4  ((EMBED*EMBED)/4)   // 262,144
#define GN4  (32*64*64/4)        // 32,768
__global__ __launch_bounds__(256)
void conv_inputs(const float* __restrict__ x, const float* __restrict__ Win,
                 __hip_bfloat16* __restrict__ xb, __hip_bfloat16* __restrict__ Winb,
                 float* __restrict__ G) {
    const long i4 = (long)blockIdx.x * 256 + threadIdx.x;  // float4 index
    if (i4 < GN4)
        *(float4v*)(G + i4 * 4) = (float4v){0.f, 0.f, 0.f, 0.f};
    float4v v;
    __hip_bfloat16* dst;
    if (i4 < XN4) {
        v = *(const float4v*)(x + i4 * 4);
        dst = xb + i4 * 4;
    } else {
        const long j = i4 - XN4;
        v = *(const float4v*)(Win + j * 4);
        dst = Winb + j * 4;
    }
    short4v o;
#pragma unroll
    for (int u = 0; u < 4; u++)
        ((__hip_bfloat16*)&o)[u] = __float2bfloat16(v[u]);
    *(short4v*)dst = o;
}

// ---------------------------------------------------------------------------
// GEMM: C[m][n] = sum_k A[m][k]*B[n][k] + bias[n]  (row-major, B^T input)
// 128x64 tile, BK=64, XCD-aware flat-grid swizzle, XOR-swizzled LDS,
// double-buffered (s_barrier + vmcnt(6)), 2 blocks/CU.
// DO_GRAM (GEMM1 only): block's n-tile == one head -> transpose own P-tile
// into LDS (bf16, identical rounding to stored P) and atomicAdd its local
// 64x64 Gram G[b,h] += P_tile^T P_tile via 16 MFMA. Replaces gram kernel.
// ---------------------------------------------------------------------------
template <typename CT, bool DO_GRAM>
__global__ __launch_bounds__(256)
void gemm_bt_bias(const __hip_bfloat16* __restrict__ A,
                  const __hip_bfloat16* __restrict__ B,
                  const float* __restrict__ bias,
                  CT* __restrict__ C,
                  float* __restrict__ G,
                  int K, int nstore, int cstride, long bstride) {
    __shared__ __hip_bfloat16 As[2][128 * 64];   // 2 x 16 KiB (also reused as Pt)
    __shared__ __hip_bfloat16 Bs[2][64 * 64];    // 2 x  8 KiB

    const int t    = threadIdx.x;
    const int blk  = blockIdx.x;            // 0..511
    const int xcd  = blk & 7;
    const int j    = blk >> 3;              // 0..63
    const int bm   = (xcd * 4 + (j & 3)) * 128;
    const int bn   = (j >> 2) * 64;
    const __hip_bfloat16* Bb = B + (long)(bm >> 11) * bstride;
    const int wave = t >> 6, lane = t & 63;
    const int wm   = (wave & 1) * 64, wn = (wave >> 1) * 32;
    const int lrow = lane & 15, lq = lane >> 4;

    const __hip_bfloat16* Arow[4];
    const __hip_bfloat16* Brow[2];
#pragma unroll
    for (int i = 0; i < 4; i++) {
        const int ci = i * 256 + t;
        const int r  = ci >> 3;
        const int sc = ((ci & 7) ^ (r & 7)) * 8;
        Arow[i] = A + (long)(bm + r) * K + sc;
    }
#pragma unroll
    for (int i = 0; i < 2; i++) {
        const int ci = i * 256 + t;
        const int r  = ci >> 3;
        const int sc = ((ci & 7) ^ (r & 7)) * 8;
        Brow[i] = Bb + (long)(bn + r) * K + sc;
    }

    float4v acc[4][2];
#pragma unroll
    for (int i = 0; i < 4; i++)
#pragma unroll
        for (int jj = 0; jj < 2; jj++) acc[i][jj] = (float4v){0.f, 0.f, 0.f, 0.f};

    const int nIter = K >> 6;   // 16

#define STAGE_TILE(k0, buf)                                                     \
    do {                                                                        \
        _Pragma("unroll")                                                       \
        for (int i = 0; i < 4; i++)                                             \
            gl2lds16(Arow[i] + (k0), (char*)As[buf] + (i * 256 + t) * 16);      \
        _Pragma("unroll")                                                       \
        for (int i = 0; i < 2; i++)                                             \
            gl2lds16(Brow[i] + (k0), (char*)Bs[buf] + (i * 256 + t) * 16);      \
    } while (0)

    STAGE_TILE(0, 0);

    for (int it = 0; it < nIter; ++it) {
        const int cur = it & 1, nxt = cur ^ 1;
        if (it + 1 < nIter) {
            STAGE_TILE((it + 1) << 6, nxt);
            WAITVM6();
        } else {
            WAITVM0();
        }
        BAR();

        const __hip_bfloat16* Ac = As[cur];
        const __hip_bfloat16* Bc = Bs[cur];
#pragma unroll
        for (int kk = 0; kk < 2; kk++) {
            short8 af[4], bf[2];
#pragma unroll
            for (int i = 0; i < 4; i++) {
                const int row = wm + i * 16 + lrow;
                const int sc  = (kk * 4 + lq) ^ (row & 7);
                af[i] = *(const short8*)(Ac + row * 64 + sc * 8);
            }
#pragma unroll
            for (int jj = 0; jj < 2; jj++) {
                const int row = wn + jj * 16 + lrow;
                const int sc  = (kk * 4 + lq) ^ (row & 7);
                bf[jj] = *(const short8*)(Bc + row * 64 + sc * 8);
            }
#pragma unroll
            for (int i = 0; i < 4; i++)
#pragma unroll
                for (int jj = 0; jj < 2; jj++)
                    acc[i][jj] = __builtin_amdgcn_mfma_f32_16x16x32_bf16(af[i], bf[jj], acc[i][jj], 0, 0, 0);
        }
        BAR();
    }
#undef STAGE_TILE

    // epilogue: C/D layout col=lane&15, row=lq*4+reg
    float bv[2];
#pragma unroll
    for (int jj = 0; jj < 2; jj++) {
        const int gn = bn + wn + jj * 16 + lrow;
        bv[jj] = (gn < nstore) ? bias[gn] : 0.f;
    }

    if (DO_GRAM) {
        // transpose this block's bf16 P-tile into LDS: Pt[n 0..63][m 0..127]
        __hip_bfloat16* Pt = (__hip_bfloat16*)As;   // stride 132 (264 B rows)
#pragma unroll
        for (int i = 0; i < 4; i++) {
            const int m0 = wm + i * 16 + lq * 4;
#pragma unroll
            for (int jj = 0; jj < 2; jj++) {
                const int n = wn + jj * 16 + lrow;
                unsigned* dst = (unsigned*)(Pt + n * 132 + m0);
                dst[0] = packbf2(acc[i][jj][0] + bv[jj], acc[i][jj][1] + bv[jj]);
                dst[1] = packbf2(acc[i][jj][2] + bv[jj], acc[i][jj][3] + bv[jj]);
            }
        }
        __syncthreads();
    }

    // global C stores (in flight while gram MFMA runs below)
#pragma unroll
    for (int i = 0; i < 4; i++) {
        const int gm0 = bm + wm + i * 16 + lq * 4;
#pragma unroll
        for (int jj = 0; jj < 2; jj++) {
            const int gn = bn + wn + jj * 16 + lrow;
            if (gn < nstore) {
#pragma unroll
                for (int r = 0; r < 4; r++)
                    storeC(&C[(long)(gm0 + r) * cstride + gn], acc[i][jj][r] + bv[jj]);
            }
        }
    }

    if (DO_GRAM) {
        const __hip_bfloat16* Pt = (const __hip_bfloat16*)As;
        float4v g4[4];
#pragma unroll
        for (int t2 = 0; t2 < 4; t2++) g4[t2] = (float4v){0.f, 0.f, 0.f, 0.f};
        const int d1l = wave * 16 + lrow;   // wave's d1 band, A-operand lane row
#pragma unroll
        for (int k0 = 0; k0 < 128; k0 += 32) {
            short8 af = lds8u(Pt + d1l * 132 + k0 + lq * 8);
#pragma unroll
            for (int t2 = 0; t2 < 4; t2++) {
                short8 bfr = lds8u(Pt + (t2 * 16 + lrow) * 132 + k0 + lq * 8);
                g4[t2] = __builtin_amdgcn_mfma_f32_16x16x32_bf16(af, bfr, g4[t2], 0, 0, 0);
            }
        }
        float* Gh = G + (long)((bm >> 11) * 16 + (bn >> 6)) * 4096;
        const int d1b = wave * 16 + lq * 4;
#pragma unroll
        for (int t2 = 0; t2 < 4; t2++) {
            const int d2 = t2 * 16 + lrow;
#pragma unroll
            for (int r = 0; r < 4; r++)
                atomicAdd(&Gh[(d1b + r) * 64 + d2], g4[t2][r]);
        }
    }
}

// ---------------------------------------------------------------------------
// Weff (MFMA): WeffT[b][n][64h+d1] = scale * sum_d Wout[n][d+64h] * G[b,h][d][d1]
// Uses G symmetry: C[n][d1] = sum_d Wl[n][d] * Gl[d1][d] -> both operands
// k-contiguous, no transpose. Wout fp32->bf16, G fp32->bf16 staged in LDS.
// ---------------------------------------------------------------------------
__global__ __launch_bounds__(256)
void weff_kernel(const float* __restrict__ Wout, const float* __restrict__ G,
                 __hip_bfloat16* __restrict__ WeffT) {
    const int n0 = blockIdx.x * 64;
    const int h  = blockIdx.y;
    const int b  = blockIdx.z;
    const float* Gh = G + (b * 16 + h) * 4096;

    __shared__ __hip_bfloat16 Wl[64 * 72];   // rows n, 72-stride (144 B)
    __shared__ __hip_bfloat16 Gl[64 * 72];   // rows d1
    const int t = threadIdx.x;

#pragma unroll
    for (int it = 0; it < 4; it++) {
        const int ci = it * 256 + t;
        const int r = ci >> 4, c4 = (ci & 15) * 4;
        // Wout slice (guard padded rows)
        float4v v = (float4v){0.f, 0.f, 0.f, 0.f};
        if (n0 + r < NCLS)
            v = *(const float4v*)(Wout + (long)(n0 + r) * EMBED + h * HDIM + c4);
        *(uint2*)(Wl + r * 72 + c4) = (uint2){packbf2(v[0], v[1]), packbf2(v[2], v[3])};
        // G slice
        float4v g = *(const float4v*)(Gh + r * 64 + c4);
        *(uint2*)(Gl + r * 72 + c4) = (uint2){packbf2(g[0], g[1]), packbf2(g[2], g[3])};
    }
    __syncthreads();

    const int wave = t >> 6, lane = t & 63;
    const int lrow = lane & 15, lq = lane >> 4;
    float4v acc[4];
#pragma unroll
    for (int jj = 0; jj < 4; jj++) acc[jj] = (float4v){0.f, 0.f, 0.f, 0.f};

#pragma unroll
    for (int k0 = 0; k0 < 64; k0 += 32) {
        short8 af = *(const short8*)(Wl + (wave * 16 + lrow) * 72 + k0 + lq * 8);
#pragma unroll
        for (int jj = 0; jj < 4; jj++) {
            short8 bfr = *(const short8*)(Gl + (jj * 16 + lrow) * 72 + k0 + lq * 8);
            acc[jj] = __builtin_amdgcn_mfma_f32_16x16x32_bf16(af, bfr, acc[jj], 0, 0, 0);
        }
    }

    const float scale = 1.0f / 32.0f;  // 1/sqrt(EMBED)
    __hip_bfloat16* Wt = WeffT + (long)b * EMBED * NPAD;
#pragma unroll
    for (int jj = 0; jj < 4; jj++) {
        const int d1 = jj * 16 + lrow;
#pragma unroll
        for (int r = 0; r < 4; r++) {
            const int n = n0 + wave * 16 + lq * 4 + r;
            Wt[(long)n * EMBED + h * HDIM + d1] = __float2bfloat16(acc[jj][r] * scale);
        }
    }
}

// ---------------------------------------------------------------------------
extern "C" void kernel_launch(void* const* d_in, const int* in_sizes, int n_in,
                              void* d_out, int out_size, void* d_ws, size_t ws_size,
                              hipStream_t stream) {
    const float* x     = (const float*)d_in[0];
    const float* W_in  = (const float*)d_in[1];
    const float* b_in  = (const float*)d_in[2];
    const float* W_out = (const float*)d_in[3];
    const float* b_out = (const float*)d_in[4];
    float* out = (float*)d_out;

    char* ws = (char*)d_ws;
    __hip_bfloat16* xb    = (__hip_bfloat16*)(ws);                 // 8 MiB
    __hip_bfloat16* Winb  = (__hip_bfloat16*)(ws + (8u  << 20));   // 2 MiB
    __hip_bfloat16* P     = (__hip_bfloat16*)(ws + (10u << 20));   // 8 MiB
    float*          G     = (float*)(ws + (18u << 20));            // 512 KiB
    __hip_bfloat16* WeffT = (__hip_bfloat16*)(ws + (19u << 20));   // 4 MiB (2 batches)

    // 1) fp32->bf16 converts + G zero
    conv_inputs<<<(XN4 + WN4) / 256, 256, 0, stream>>>(x, W_in, xb, Winb, G);
    // 2) P = x @ W_in^T + b_in  [4096x1024] bf16; fused per-tile Gram atomics
    gemm_bt_bias<__hip_bfloat16, true><<<512, 256, 0, stream>>>(
        xb, Winb, b_in, P, G, EMBED, NPAD, NPAD, 0);
    // 3) WeffT[b] = scale * (G . Wout^T) per head block (MFMA)
    weff_kernel<<<dim3(16, 16, 2), 256, 0, stream>>>(W_out, G, WeffT);
    // 4) out = P @ WeffT^T + b_out  [4096x1000] fp32, batch-strided B
    gemm_bt_bias<float, false><<<512, 256, 0, stream>>>(
        P, WeffT, b_out, out, nullptr, EMBED, NCLS, NCLS, (long)EMBED * NPAD);
}